// Round 1
// baseline (83.725 us; speedup 1.0000x reference)
//
#include <hip/hip_runtime.h>
#include <math.h>

namespace {

constexpr int M = 8;    // antennas
constexpr int K = 3;    // streams
constexpr int P = 16;   // QAM-16
constexpr int NB = 4;   // bits per symbol

// One block per batch element. 256 threads = 4 waves.
// Wave 0: cooperative 8x8 complex Cholesky of S (lane i holds row i) and
//         forward solves L z = [y, h0, h1, h2] (lanes 0..3, one RHS each).
// Then all 256 threads: thread t = (s0 = t>>4, s1 = t&15) evaluates the 16
// candidates (s0,s1,s2=j) via the factorized distance
//   e = -( ||part||^2 - 2 Re(conj(p2) cp) + |p2|^2 ||ht2||^2 ),
//   part = yt - ht0*p0 - ht1*p1,  cp = <part, ht2>.
// Grouped logsumexp done with one global max shift (cancels in the final
// LLR = log(sum c1) - log(sum c0)).
__global__ __launch_bounds__(256, 1) void mld_kernel(
    const float* __restrict__ y_re, const float* __restrict__ y_im,
    const float* __restrict__ h_re, const float* __restrict__ h_im,
    const float* __restrict__ s_re, const float* __restrict__ s_im,
    const float* __restrict__ vecs_re, const float* __restrict__ vecs_im,
    const int* __restrict__ c1, const int* __restrict__ c0,
    float* __restrict__ out)
{
  const int b    = blockIdx.x;
  const int tid  = threadIdx.x;
  const int lane = tid & 63;
  const int wave = tid >> 6;

  __shared__ float2 sYt[M];        // L^-1 y
  __shared__ float2 sHt[K][M];     // L^-1 h, per stream
  __shared__ float2 sPts[P];       // constellation points
  __shared__ float  sPp[P];        // |point|^2
  __shared__ float  sSums[3 * P];  // per-(k,s) exp-sums
  __shared__ float  sWred[4];      // per-wave max

  if (wave == 0) {
    // ---- Cholesky: S = L L^H, lane i (mod 8) owns row i ----
    const int i = lane & 7;
    float2 Srow[8];
    float2 Lrow[8];
    #pragma unroll
    for (int p = 0; p < 8; ++p)
      Srow[p] = make_float2(s_re[b*64 + i*8 + p], s_im[b*64 + i*8 + p]);

    #pragma unroll
    for (int j = 0; j < 8; ++j) {
      float2 a = Srow[j];
      #pragma unroll
      for (int p = 0; p < j; ++p) {
        const float ljx = __shfl(Lrow[p].x, j);  // L[j][p]
        const float ljy = __shfl(Lrow[p].y, j);
        // a -= L[i][p] * conj(L[j][p])
        a.x -= Lrow[p].x * ljx + Lrow[p].y * ljy;
        a.y -= Lrow[p].y * ljx - Lrow[p].x * ljy;
      }
      const float d   = sqrtf(__shfl(a.x, j));   // diag (real, >= 1)
      const float inv = 1.0f / d;
      Lrow[j] = (i == j) ? make_float2(d, 0.0f)
                         : make_float2(a.x * inv, a.y * inv);
    }

    // ---- forward substitution, RHS r = lane&3 (0:y, 1..3:h cols) ----
    const int r = lane & 3;
    float2 z[8];
    #pragma unroll
    for (int j = 0; j < 8; ++j) {
      float2 acc;
      if (r == 0) acc = make_float2(y_re[b*8 + j], y_im[b*8 + j]);
      else        acc = make_float2(h_re[b*24 + j*3 + (r-1)],
                                    h_im[b*24 + j*3 + (r-1)]);
      #pragma unroll
      for (int p = 0; p < j; ++p) {
        const float ljx = __shfl(Lrow[p].x, j);  // L[j][p]
        const float ljy = __shfl(Lrow[p].y, j);
        // acc -= L[j][p] * z[p]
        acc.x -= ljx * z[p].x - ljy * z[p].y;
        acc.y -= ljx * z[p].y + ljy * z[p].x;
      }
      const float dinv = 1.0f / __shfl(Lrow[j].x, j);
      z[j] = make_float2(acc.x * dinv, acc.y * dinv);
    }
    if (lane < 4) {
      #pragma unroll
      for (int j = 0; j < 8; ++j) {
        if (r == 0) sYt[j]      = z[j];
        else        sHt[r-1][j] = z[j];
      }
    }
  } else if (wave == 1) {
    if (lane < P) {
      // pts[s] = vecs[v=s][k=2] (digits (0,0,s))
      const float px = vecs_re[lane*3 + 2];
      const float py = vecs_im[lane*3 + 2];
      sPts[lane] = make_float2(px, py);
      sPp[lane]  = px*px + py*py;
    }
  } else if (wave == 2) {
    if (lane < 3*P) sSums[lane] = 0.0f;
  }
  __syncthreads();

  // ---- per-thread candidate evaluation ----
  const int s0 = tid >> 4;
  const int s1 = tid & 15;
  const float2 p0 = sPts[s0];
  const float2 p1 = sPts[s1];

  float np = 0.0f;           // ||part||^2
  float cpx = 0.0f, cpy = 0.0f;  // <part, ht2> = sum part*conj(ht2)
  float n2 = 0.0f;           // ||ht2||^2
  #pragma unroll
  for (int m = 0; m < 8; ++m) {
    const float2 yt = sYt[m];
    const float2 h0 = sHt[0][m];
    const float2 h1 = sHt[1][m];
    const float2 h2 = sHt[2][m];
    const float prx = yt.x - (h0.x*p0.x - h0.y*p0.y) - (h1.x*p1.x - h1.y*p1.y);
    const float pry = yt.y - (h0.x*p0.y + h0.y*p0.x) - (h1.x*p1.y + h1.y*p1.x);
    np  += prx*prx + pry*pry;
    cpx += prx*h2.x + pry*h2.y;
    cpy += pry*h2.x - prx*h2.y;
    n2  += h2.x*h2.x + h2.y*h2.y;
  }

  float e[16];
  float lmax = -1e30f;
  #pragma unroll
  for (int j = 0; j < 16; ++j) {
    const float2 p2 = sPts[j];
    const float ev = -(np - 2.0f*(cpx*p2.x + cpy*p2.y) + sPp[j]*n2);
    e[j] = ev;
    lmax = fmaxf(lmax, ev);
  }

  // ---- global max reduction ----
  float wm = lmax;
  #pragma unroll
  for (int off = 32; off; off >>= 1) wm = fmaxf(wm, __shfl_xor(wm, off));
  if (lane == 0) sWred[wave] = wm;
  __syncthreads();
  const float gmax = fmaxf(fmaxf(sWred[0], sWred[1]),
                           fmaxf(sWred[2], sWred[3]));

  // ---- exp + grouped sums ----
  float pv[16];
  float ssum = 0.0f;
  #pragma unroll
  for (int j = 0; j < 16; ++j) {
    pv[j] = __expf(e[j] - gmax);
    ssum += pv[j];
  }

  // k=0 groups: 16 consecutive lanes share s0
  float v0 = ssum;
  v0 += __shfl_xor(v0, 1); v0 += __shfl_xor(v0, 2);
  v0 += __shfl_xor(v0, 4); v0 += __shfl_xor(v0, 8);
  if ((lane & 15) == 0) atomicAdd(&sSums[s0], v0);

  // k=1 groups: lanes with equal (lane&15) across the wave share s1
  float v1 = ssum;
  v1 += __shfl_xor(v1, 16); v1 += __shfl_xor(v1, 32);
  if (lane < 16) atomicAdd(&sSums[P + s1], v1);

  // k=2 groups: full-wave reduce per j
  #pragma unroll
  for (int j = 0; j < 16; ++j) {
    float v = pv[j];
    v += __shfl_xor(v, 1);  v += __shfl_xor(v, 2);
    v += __shfl_xor(v, 4);  v += __shfl_xor(v, 8);
    v += __shfl_xor(v, 16); v += __shfl_xor(v, 32);
    if (lane == 0) atomicAdd(&sSums[2*P + j], v);
  }
  __syncthreads();

  // ---- LLRs: gmax cancels in the difference of logs ----
  if (tid < 12) {
    const int k   = tid >> 2;
    const int bit = tid & 3;
    float a1 = 0.0f, a0 = 0.0f;
    #pragma unroll
    for (int t = 0; t < 8; ++t) {
      a1 += sSums[k*P + c1[bit*8 + t]];
      a0 += sSums[k*P + c0[bit*8 + t]];
    }
    out[b*12 + tid] = logf(a1) - logf(a0);
  }
}

} // namespace

extern "C" void kernel_launch(void* const* d_in, const int* in_sizes, int n_in,
                              void* d_out, int out_size, void* d_ws, size_t ws_size,
                              hipStream_t stream) {
  const float* y_re    = (const float*)d_in[0];
  const float* y_im    = (const float*)d_in[1];
  const float* h_re    = (const float*)d_in[2];
  const float* h_im    = (const float*)d_in[3];
  const float* s_re    = (const float*)d_in[4];
  const float* s_im    = (const float*)d_in[5];
  const float* vecs_re = (const float*)d_in[6];
  const float* vecs_im = (const float*)d_in[7];
  // d_in[8] = c (derived analytically from digit structure; unused)
  const int* c1 = (const int*)d_in[9];
  const int* c0 = (const int*)d_in[10];
  float* out = (float*)d_out;

  const int B = in_sizes[0] / M;  // 1024
  mld_kernel<<<dim3(B), dim3(256), 0, stream>>>(
      y_re, y_im, h_re, h_im, s_re, s_im, vecs_re, vecs_im, c1, c0, out);
}